// Round 1
// baseline (32207.220 us; speedup 1.0000x reference)
//
#include <hip/hip_runtime.h>
#include <hip/hip_bf16.h>

#define B_ 64
#define T_ 256
#define D_ 200
#define H_ 300
#define L_ 8
#define M_ 16384      // T_*B_
#define NG 1800       // 6H
#define NZ 1500       // 5H

typedef __attribute__((ext_vector_type(8))) short bf16x8;
typedef __attribute__((ext_vector_type(4))) float f32x4;

__device__ __forceinline__ unsigned short f2bf(float f) {
  union { float f; unsigned u; } v; v.f = f;
  unsigned r = v.u + 0x7fffu + ((v.u >> 16) & 1u);   // RNE
  return (unsigned short)(r >> 16);
}

__device__ __forceinline__ float sigf(float x) { return 1.f / (1.f + __expf(-x)); }
__device__ __forceinline__ float tanhf_(float x) {
  x = fminf(15.f, fmaxf(-15.f, x));
  float e = __expf(2.f * x);
  return (e - 1.f) / (e + 1.f);
}

// ---- weight conversion: W_ih0 (200x1800) then W_ih_rest (7x300x1800) -> bf16 ----
__global__ void k_convert_w(const float* __restrict__ W0, const float* __restrict__ Wr,
                            unsigned short* __restrict__ Wb) {
  int i = blockIdx.x * blockDim.x + threadIdx.x;
  const int n0 = D_ * NG;            // 360000
  const int n1 = (L_ - 1) * H_ * NG; // 3780000
  if (i < n0) Wb[i] = f2bf(W0[i]);
  else if (i < n0 + n1) Wb[i] = f2bf(Wr[i - n0]);
}

// ---- inputs [B,T,D] fp32 -> time-major xb [T,B,D] bf16 ----
__global__ void k_transpose_in(const float* __restrict__ inp, unsigned short* __restrict__ xb) {
  int i = blockIdx.x * blockDim.x + threadIdx.x;     // over T_*B_*D_
  if (i >= T_ * B_ * D_) return;
  int d = i % D_;
  int r = i / D_;       // t*B_+b
  int b = r % B_;
  int t = r / B_;
  xb[i] = f2bf(inp[((size_t)b * T_ + t) * D_ + d]);
}

// ---- previous layer ys [T,B,H] fp32 -> xb bf16 (same row order) ----
__global__ void k_conv_x(const float* __restrict__ src, unsigned short* __restrict__ xb) {
  int i = blockIdx.x * blockDim.x + threadIdx.x;
  if (i < M_ * H_) xb[i] = f2bf(src[i]);
}

// ---- hidden[7] [T,B,H] -> output [B,T,H] ----
__global__ void k_out(const float* __restrict__ hid7, float* __restrict__ outp) {
  int i = blockIdx.x * blockDim.x + threadIdx.x;     // over B_*T_*H_
  if (i >= B_ * T_ * H_) return;
  int j = i % H_;
  int r = i / H_;
  int t = r % T_;
  int b = r / T_;
  outp[i] = hid7[((size_t)t * B_ + b) * H_ + j];
}

// ---- pi GEMM: C[M,1800] fp32 = A[M,K] bf16 * B[K,1800] bf16 ----
// 64x64 tile, 256 thr = 4 waves (2x2), mfma_f32_16x16x32_bf16.
// Verified layouts: A[m=lane&15][k=quad*8+j]; B[k=quad*8+j][n=lane&15]; D[row=quad*4+reg][col=lane&15]
__global__ __launch_bounds__(256) void k_gemm(const unsigned short* __restrict__ A,
                                              const unsigned short* __restrict__ Bw,
                                              float* __restrict__ C, int K) {
  __shared__ unsigned short As[64 * 40];  // row-major [m][k], stride 40 (80B: 16B-aligned, 2-way banks)
  __shared__ unsigned short Bs[64 * 40];  // transposed [n][k], stride 40
  int bm = blockIdx.x, bn = blockIdx.y;
  int tid = threadIdx.x;
  int lane = tid & 63, wid = tid >> 6;
  int wm = wid & 1, wn = wid >> 1;
  int l16 = lane & 15, quad = lane >> 4;
  f32x4 acc00 = {0,0,0,0}, acc01 = {0,0,0,0}, acc10 = {0,0,0,0}, acc11 = {0,0,0,0};
  int nk = (K + 31) >> 5;
  for (int kc = 0; kc < nk; kc++) {
    int k0 = kc << 5;
    // stage A: 512 chunks of 4 bf16 (8B)
    #pragma unroll
    for (int c0 = 0; c0 < 2; c0++) {
      int c = tid + c0 * 256;
      int m = c >> 3, kq = (c & 7) << 2;
      int kk = k0 + kq;
      uint2 val = make_uint2(0u, 0u);
      if (kk < K) val = *(const uint2*)(A + (size_t)(bm * 64 + m) * K + kk);
      *(uint2*)(&As[m * 40 + kq]) = val;
    }
    // stage B transposed
    #pragma unroll
    for (int c0 = 0; c0 < 2; c0++) {
      int c = tid + c0 * 256;
      int krow = c >> 4, nq = (c & 15) << 2;
      int col = bn * 64 + nq;
      uint2 val = make_uint2(0u, 0u);
      if ((k0 + krow) < K && col < NG)
        val = *(const uint2*)(Bw + (size_t)(k0 + krow) * NG + col);
      const unsigned short* pv = (const unsigned short*)&val;
      Bs[(nq + 0) * 40 + krow] = pv[0];
      Bs[(nq + 1) * 40 + krow] = pv[1];
      Bs[(nq + 2) * 40 + krow] = pv[2];
      Bs[(nq + 3) * 40 + krow] = pv[3];
    }
    __syncthreads();
    bf16x8 a0 = *(const bf16x8*)&As[(wm * 32 + l16) * 40 + quad * 8];
    bf16x8 a1 = *(const bf16x8*)&As[(wm * 32 + 16 + l16) * 40 + quad * 8];
    bf16x8 b0 = *(const bf16x8*)&Bs[(wn * 32 + l16) * 40 + quad * 8];
    bf16x8 b1 = *(const bf16x8*)&Bs[(wn * 32 + 16 + l16) * 40 + quad * 8];
    acc00 = __builtin_amdgcn_mfma_f32_16x16x32_bf16(a0, b0, acc00, 0, 0, 0);
    acc01 = __builtin_amdgcn_mfma_f32_16x16x32_bf16(a0, b1, acc01, 0, 0, 0);
    acc10 = __builtin_amdgcn_mfma_f32_16x16x32_bf16(a1, b0, acc10, 0, 0, 0);
    acc11 = __builtin_amdgcn_mfma_f32_16x16x32_bf16(a1, b1, acc11, 0, 0, 0);
    __syncthreads();
  }
  int rowb = bm * 64 + wm * 32 + quad * 4;
  int colb = bn * 64 + wn * 32 + l16;
  #pragma unroll
  for (int i = 0; i < 4; i++) {
    if (colb < NG) {
      C[(size_t)(rowb + i) * NG + colb] = acc00[i];
      C[(size_t)(rowb + 16 + i) * NG + colb] = acc10[i];
    }
    if (colb + 16 < NG) {
      C[(size_t)(rowb + i) * NG + colb + 16] = acc01[i];
      C[(size_t)(rowb + 16 + i) * NG + colb + 16] = acc11[i];
    }
  }
}

// ---- persistent recurrence: 192 blocks = 16 batch-groups (4 rows) x 12 column-blocks (25 j's) ----
// W_hh slice register-resident (75 fp32/thread). Per-group double-buffered h in global +
// monotonic arrival counter (agent-scope atomics) for cross-block sync.
__global__ __launch_bounds__(512, 2) void k_recur(
    const float* __restrict__ pi, const float* __restrict__ Whh,
    const float* __restrict__ bias, const int* __restrict__ lens,
    float* __restrict__ hid, float* __restrict__ h_buf,
    unsigned* __restrict__ arrive, int rev)
{
  __shared__ float lds_h[4 * 308];   // [r][ks*76+kk] (padded so each k-slice is 16B aligned)
  __shared__ float zpart[16 * 128];  // [ks][r][cc]
  __shared__ float zfull[4 * 128];   // [r][cc]
  __shared__ float c_lds[100];       // [r][jj]
  __shared__ float bias_s[128];
  __shared__ int len_s[4];

  const int tid = threadIdx.x;
  const int bid = blockIdx.x;
  const int g = bid & 15;    // batch group (same-XCD under round-robin)
  const int cb = bid >> 4;   // column block 0..11

  const int cc = tid & 127;
  const int ks = tid >> 7;
  const bool ccv = cc < 125;
  const int gate = cc / 25;
  const int jj = cc % 25;
  const int colg = gate * 300 + cb * 25 + jj;   // z column [0,1500)

  const int r2 = tid / 125;                     // z-sum mapping (tid<500)
  const int cc2 = tid - r2 * 125;
  const int colg2 = (cc2 / 25) * 300 + cb * 25 + (cc2 % 25);

  const int gr = tid / 25;                      // gate mapping (tid<100)
  const int gj = tid - gr * 25;
  const int j2 = cb * 25 + gj;

  float w[75];
  if (ccv) {
    #pragma unroll
    for (int kk = 0; kk < 75; kk++)
      w[kk] = Whh[(size_t)(ks * 75 + kk) * NZ + colg];
  }
  if (tid < 4) len_s[tid] = lens[g * 4 + tid];
  if (tid < 125) bias_s[tid] = bias[colg];
  if (tid < 100) c_lds[tid] = 0.f;
  __syncthreads();

  int S = len_s[0];
  S = len_s[1] > S ? len_s[1] : S;
  S = len_s[2] > S ? len_s[2] : S;
  S = len_s[3] > S ? len_s[3] : S;
  unsigned* arr = arrive + g;
  const int brbase = g * 4;

  for (int s = 0; s < S; s++) {
    // prefetch pi for this step (in flight across the spin-wait)
    float pi_pre = 0.f, pi6_pre = 0.f;
    if (tid < 500) {
      int lr = len_s[r2];
      if (s < lr) {
        int t = rev ? (lr - 1 - s) : s;
        pi_pre = pi[((size_t)t * B_ + (brbase + r2)) * NG + colg2];
      }
    }
    if (tid < 100) {
      int lr = len_s[gr];
      if (s < lr) {
        int t = rev ? (lr - 1 - s) : s;
        pi6_pre = pi[((size_t)t * B_ + (brbase + gr)) * NG + NZ + j2];
      }
    }

    if (s > 0) {
      unsigned target = (unsigned)(12 * s);
      while (__hip_atomic_load(arr, __ATOMIC_RELAXED, __HIP_MEMORY_SCOPE_AGENT) < target)
        __builtin_amdgcn_s_sleep(1);
      (void)__hip_atomic_load(arr, __ATOMIC_ACQUIRE, __HIP_MEMORY_SCOPE_AGENT);
      const float* src = h_buf + (size_t)(s & 1) * B_ * H_ + (size_t)brbase * H_;
      for (int i = tid; i < 1200; i += 512) {
        int r = i / 300;
        int k = i - r * 300;
        int kks = k / 75;
        int kkr = k - kks * 75;
        lds_h[r * 308 + kks * 76 + kkr] = src[i];
      }
    }
    __syncthreads();

    float a0 = 0.f, a1 = 0.f, a2 = 0.f, a3 = 0.f;
    if (ccv && s > 0) {
      const int kb = ks * 76;
      #pragma unroll
      for (int kk = 0; kk < 72; kk += 4) {
        float4 h0 = *(const float4*)&lds_h[0 * 308 + kb + kk];
        float4 h1 = *(const float4*)&lds_h[1 * 308 + kb + kk];
        float4 h2 = *(const float4*)&lds_h[2 * 308 + kb + kk];
        float4 h3 = *(const float4*)&lds_h[3 * 308 + kb + kk];
        float w0 = w[kk], w1 = w[kk + 1], w2 = w[kk + 2], w3 = w[kk + 3];
        a0 += h0.x * w0 + h0.y * w1 + h0.z * w2 + h0.w * w3;
        a1 += h1.x * w0 + h1.y * w1 + h1.z * w2 + h1.w * w3;
        a2 += h2.x * w0 + h2.y * w1 + h2.z * w2 + h2.w * w3;
        a3 += h3.x * w0 + h3.y * w1 + h3.z * w2 + h3.w * w3;
      }
      #pragma unroll
      for (int kk = 72; kk < 75; kk++) {
        float wv = w[kk];
        a0 += lds_h[0 * 308 + kb + kk] * wv;
        a1 += lds_h[1 * 308 + kb + kk] * wv;
        a2 += lds_h[2 * 308 + kb + kk] * wv;
        a3 += lds_h[3 * 308 + kb + kk] * wv;
      }
    }
    if (ccv) {
      zpart[(ks * 4 + 0) * 128 + cc] = a0;
      zpart[(ks * 4 + 1) * 128 + cc] = a1;
      zpart[(ks * 4 + 2) * 128 + cc] = a2;
      zpart[(ks * 4 + 3) * 128 + cc] = a3;
    }
    __syncthreads();
    if (tid < 500) {
      float z = zpart[(0 * 4 + r2) * 128 + cc2] + zpart[(1 * 4 + r2) * 128 + cc2]
              + zpart[(2 * 4 + r2) * 128 + cc2] + zpart[(3 * 4 + r2) * 128 + cc2]
              + pi_pre + bias_s[cc2];
      zfull[r2 * 128 + cc2] = z;
    }
    __syncthreads();
    if (tid < 100) {
      int lr = len_s[gr];
      if (s < lr) {
        float zi = zfull[gr * 128 + gj];
        float zf = zfull[gr * 128 + 25 + gj];
        float zg = zfull[gr * 128 + 50 + gj];
        float zo = zfull[gr * 128 + 75 + gj];
        float zr = zfull[gr * 128 + 100 + gj];
        float ii = sigf(zi), ff = sigf(zf), gg = tanhf_(zg);
        float oo = sigf(zo), rr = sigf(zr);
        float cn = ii * gg + ff * c_lds[tid];
        c_lds[tid] = cn;
        float hn = rr * (oo * tanhf_(cn)) + (1.f - rr) * pi6_pre;
        int t = rev ? (lr - 1 - s) : s;
        int br = brbase + gr;
        h_buf[(size_t)((s + 1) & 1) * B_ * H_ + (size_t)br * H_ + j2] = hn;
        hid[((size_t)t * B_ + br) * H_ + j2] = hn;
      }
    }
    __syncthreads();
    if (tid == 0)
      __hip_atomic_fetch_add(arr, 1u, __ATOMIC_RELEASE, __HIP_MEMORY_SCOPE_AGENT);
  }
}

extern "C" void kernel_launch(void* const* d_in, const int* in_sizes, int n_in,
                              void* d_out, int out_size, void* d_ws, size_t ws_size,
                              hipStream_t stream) {
  const float* inputs = (const float*)d_in[0];
  const int* lengths = (const int*)d_in[1];
  const float* W_ih0 = (const float*)d_in[2];
  const float* W_ih_rest = (const float*)d_in[3];
  const float* W_hh = (const float*)d_in[4];
  const float* b_hh = (const float*)d_in[5];
  float* outp = (float*)d_out;
  float* hidden = outp + (size_t)B_ * T_ * H_;   // [L][T,B,H]

  char* ws = (char*)d_ws;
  float* pi = (float*)ws;                                         // M_*NG fp32 (118MB)
  size_t off = (size_t)M_ * NG * 4;
  unsigned short* xb = (unsigned short*)(ws + off);               // M_*H_ bf16
  off += (size_t)M_ * H_ * 2;
  unsigned short* Wb = (unsigned short*)(ws + off);               // 4,140,000 bf16
  off += 4140000ull * 2;
  float* h_buf = (float*)(ws + off);                              // 2*64*300 fp32
  off += 2ull * B_ * H_ * 4;
  unsigned* arrive = (unsigned*)(ws + off);                       // 8*16 counters

  hipMemsetAsync(d_out, 0, (size_t)out_size * 4, stream);         // zero padding regions
  hipMemsetAsync(arrive, 0, L_ * 16 * 4, stream);

  {
    int n = D_ * NG + (L_ - 1) * H_ * NG;
    k_convert_w<<<(n + 255) / 256, 256, 0, stream>>>(W_ih0, W_ih_rest, Wb);
  }
  {
    int n = T_ * B_ * D_;
    k_transpose_in<<<(n + 255) / 256, 256, 0, stream>>>(inputs, xb);
  }
  for (int l = 0; l < L_; l++) {
    const unsigned short* Wihb = (l == 0) ? Wb : (Wb + 360000 + (size_t)(l - 1) * 540000);
    int K = (l == 0) ? D_ : H_;
    k_gemm<<<dim3(M_ / 64, (NG + 63) / 64), 256, 0, stream>>>(xb, Wihb, pi, K);
    float* hid_l = hidden + (size_t)l * T_ * B_ * H_;
    k_recur<<<192, 512, 0, stream>>>(pi, W_hh + (size_t)l * H_ * NZ, b_hh + (size_t)l * NZ,
                                     lengths, hid_l, h_buf, arrive + l * 16, l & 1);
    if (l < L_ - 1) {
      int n = M_ * H_;
      k_conv_x<<<(n + 255) / 256, 256, 0, stream>>>(hid_l, xb);
    }
  }
  k_out<<<((B_ * T_ * H_) + 255) / 256, 256, 0, stream>>>(
      hidden + (size_t)(L_ - 1) * T_ * B_ * H_, outp);
}

// Round 2
// 8987.083 us; speedup vs baseline: 3.5837x; 3.5837x over previous
//
#include <hip/hip_runtime.h>
#include <hip/hip_bf16.h>

#define B_ 64
#define T_ 256
#define D_ 200
#define H_ 300
#define L_ 8
#define M_ 16384      // T_*B_
#define NG 1800       // 6H
#define NZ 1500       // 5H

typedef __attribute__((ext_vector_type(8))) short bf16x8;
typedef __attribute__((ext_vector_type(4))) float f32x4;

__device__ __forceinline__ unsigned short f2bf(float f) {
  union { float f; unsigned u; } v; v.f = f;
  unsigned r = v.u + 0x7fffu + ((v.u >> 16) & 1u);   // RNE
  return (unsigned short)(r >> 16);
}

__device__ __forceinline__ float sigf(float x) { return 1.f / (1.f + __expf(-x)); }
__device__ __forceinline__ float tanhf_(float x) {
  x = fminf(15.f, fmaxf(-15.f, x));
  float e = __expf(2.f * x);
  return (e - 1.f) / (e + 1.f);
}

// ---- weight conversion: W_ih0 (200x1800) then W_ih_rest (7x300x1800) -> bf16 ----
__global__ void k_convert_w(const float* __restrict__ W0, const float* __restrict__ Wr,
                            unsigned short* __restrict__ Wb) {
  int i = blockIdx.x * blockDim.x + threadIdx.x;
  const int n0 = D_ * NG;            // 360000
  const int n1 = (L_ - 1) * H_ * NG; // 3780000
  if (i < n0) Wb[i] = f2bf(W0[i]);
  else if (i < n0 + n1) Wb[i] = f2bf(Wr[i - n0]);
}

// ---- inputs [B,T,D] fp32 -> time-major xb [T,B,D] bf16 ----
__global__ void k_transpose_in(const float* __restrict__ inp, unsigned short* __restrict__ xb) {
  int i = blockIdx.x * blockDim.x + threadIdx.x;     // over T_*B_*D_
  if (i >= T_ * B_ * D_) return;
  int d = i % D_;
  int r = i / D_;       // t*B_+b
  int b = r % B_;
  int t = r / B_;
  xb[i] = f2bf(inp[((size_t)b * T_ + t) * D_ + d]);
}

// ---- hidden[7] [T,B,H] -> output [B,T,H] ----
__global__ void k_out(const float* __restrict__ hid7, float* __restrict__ outp) {
  int i = blockIdx.x * blockDim.x + threadIdx.x;     // over B_*T_*H_
  if (i >= B_ * T_ * H_) return;
  int j = i % H_;
  int r = i / H_;
  int t = r % T_;
  int b = r / T_;
  outp[i] = hid7[((size_t)t * B_ + b) * H_ + j];
}

// ---- pi GEMM: C[M,1800] fp32 = A[M,K] bf16 * B[K,1800] bf16 ----
__global__ __launch_bounds__(256) void k_gemm(const unsigned short* __restrict__ A,
                                              const unsigned short* __restrict__ Bw,
                                              float* __restrict__ C, int K) {
  __shared__ unsigned short As[64 * 40];  // row-major [m][k], stride 40
  __shared__ unsigned short Bs[64 * 40];  // transposed [n][k], stride 40
  int bm = blockIdx.x, bn = blockIdx.y;
  int tid = threadIdx.x;
  int lane = tid & 63, wid = tid >> 6;
  int wm = wid & 1, wn = wid >> 1;
  int l16 = lane & 15, quad = lane >> 4;
  f32x4 acc00 = {0,0,0,0}, acc01 = {0,0,0,0}, acc10 = {0,0,0,0}, acc11 = {0,0,0,0};
  int nk = (K + 31) >> 5;
  for (int kc = 0; kc < nk; kc++) {
    int k0 = kc << 5;
    #pragma unroll
    for (int c0 = 0; c0 < 2; c0++) {
      int c = tid + c0 * 256;
      int m = c >> 3, kq = (c & 7) << 2;
      int kk = k0 + kq;
      uint2 val = make_uint2(0u, 0u);
      if (kk < K) val = *(const uint2*)(A + (size_t)(bm * 64 + m) * K + kk);
      *(uint2*)(&As[m * 40 + kq]) = val;
    }
    #pragma unroll
    for (int c0 = 0; c0 < 2; c0++) {
      int c = tid + c0 * 256;
      int krow = c >> 4, nq = (c & 15) << 2;
      int col = bn * 64 + nq;
      uint2 val = make_uint2(0u, 0u);
      if ((k0 + krow) < K && col < NG)
        val = *(const uint2*)(Bw + (size_t)(k0 + krow) * NG + col);
      const unsigned short* pv = (const unsigned short*)&val;
      Bs[(nq + 0) * 40 + krow] = pv[0];
      Bs[(nq + 1) * 40 + krow] = pv[1];
      Bs[(nq + 2) * 40 + krow] = pv[2];
      Bs[(nq + 3) * 40 + krow] = pv[3];
    }
    __syncthreads();
    bf16x8 a0 = *(const bf16x8*)&As[(wm * 32 + l16) * 40 + quad * 8];
    bf16x8 a1 = *(const bf16x8*)&As[(wm * 32 + 16 + l16) * 40 + quad * 8];
    bf16x8 b0 = *(const bf16x8*)&Bs[(wn * 32 + l16) * 40 + quad * 8];
    bf16x8 b1 = *(const bf16x8*)&Bs[(wn * 32 + 16 + l16) * 40 + quad * 8];
    acc00 = __builtin_amdgcn_mfma_f32_16x16x32_bf16(a0, b0, acc00, 0, 0, 0);
    acc01 = __builtin_amdgcn_mfma_f32_16x16x32_bf16(a0, b1, acc01, 0, 0, 0);
    acc10 = __builtin_amdgcn_mfma_f32_16x16x32_bf16(a1, b0, acc10, 0, 0, 0);
    acc11 = __builtin_amdgcn_mfma_f32_16x16x32_bf16(a1, b1, acc11, 0, 0, 0);
    __syncthreads();
  }
  int rowb = bm * 64 + wm * 32 + quad * 4;
  int colb = bn * 64 + wn * 32 + l16;
  #pragma unroll
  for (int i = 0; i < 4; i++) {
    if (colb < NG) {
      C[(size_t)(rowb + i) * NG + colb] = acc00[i];
      C[(size_t)(rowb + 16 + i) * NG + colb] = acc10[i];
    }
    if (colb + 16 < NG) {
      C[(size_t)(rowb + i) * NG + colb + 16] = acc01[i];
      C[(size_t)(rowb + 16 + i) * NG + colb + 16] = acc11[i];
    }
  }
}

// ---- persistent recurrence: 192 blocks = 16 batch-groups (4 rows) x 12 column-blocks ----
// All cross-block traffic via RELAXED agent-scope atomics (sc0/sc1: coherent at IF$,
// NO buffer_inv/wbl2 cache maintenance — that was Round-1's 15.5us/step killer).
// Per-(group,colblock) flag words instead of one RMW counter; wave 0 polls, 7 waves park.
__global__ __launch_bounds__(512, 2) void k_recur(
    const float* __restrict__ pi, const float* __restrict__ Whh,
    const float* __restrict__ bias, const int* __restrict__ lens,
    float* __restrict__ hid, unsigned short* __restrict__ xb,
    float* __restrict__ h_buf, unsigned* __restrict__ arrive, int rev)
{
  __shared__ float lds_h[4 * 308];   // [r][ks*76+kk]
  __shared__ float zpart[16 * 128];  // [ks][r][cc]
  __shared__ float zfull[4 * 128];   // [r][cc]
  __shared__ float c_lds[100];       // [r][jj]
  __shared__ float bias_s[128];
  __shared__ int len_s[4];

  const int tid = threadIdx.x;
  const int bid = blockIdx.x;
  const int g = bid & 15;    // batch group
  const int cb = bid >> 4;   // column block 0..11

  const int cc = tid & 127;
  const int ks = tid >> 7;
  const bool ccv = cc < 125;
  const int gate = cc / 25;
  const int jj = cc % 25;
  const int colg = gate * 300 + cb * 25 + jj;   // z column [0,1500)

  const int r2 = tid / 125;                     // z-sum mapping (tid<500)
  const int cc2 = tid - r2 * 125;
  const int colg2 = (cc2 / 25) * 300 + cb * 25 + (cc2 % 25);

  const int gr = tid / 25;                      // gate mapping (tid<100)
  const int gj = tid - gr * 25;
  const int j2 = cb * 25 + gj;

  float w[75];
  if (ccv) {
    #pragma unroll
    for (int kk = 0; kk < 75; kk++)
      w[kk] = Whh[(size_t)(ks * 75 + kk) * NZ + colg];
  }
  if (tid < 4) len_s[tid] = lens[g * 4 + tid];
  if (tid < 125) bias_s[tid] = bias[colg];
  if (tid < 100) c_lds[tid] = 0.f;
  __syncthreads();

  int S = len_s[0];
  S = len_s[1] > S ? len_s[1] : S;
  S = len_s[2] > S ? len_s[2] : S;
  S = len_s[3] > S ? len_s[3] : S;
  unsigned* arr_g = arrive + g * 12;            // 12 flags for this group
  const int brbase = g * 4;

  for (int s = 0; s < S; s++) {
    // prefetch pi for this step (in flight across the spin-wait)
    float pi_pre = 0.f, pi6_pre = 0.f;
    if (tid < 500) {
      int lr = len_s[r2];
      if (s < lr) {
        int t = rev ? (lr - 1 - s) : s;
        pi_pre = pi[((size_t)t * B_ + (brbase + r2)) * NG + colg2];
      }
    }
    if (tid < 100) {
      int lr = len_s[gr];
      if (s < lr) {
        int t = rev ? (lr - 1 - s) : s;
        pi6_pre = pi[((size_t)t * B_ + (brbase + gr)) * NG + NZ + j2];
      }
    }

    if (s > 0) {
      // wave 0 polls all 12 flags (relaxed, no cache maintenance); waves 1-7 park at barrier
      if (tid < 64) {
        const unsigned* f = arr_g + ((tid < 12) ? tid : 11);
        const unsigned tgt = (unsigned)s;
        for (;;) {
          unsigned v = __hip_atomic_load(f, __ATOMIC_RELAXED, __HIP_MEMORY_SCOPE_AGENT);
          if (__all((int)(v >= tgt))) break;
        }
      }
      __syncthreads();
      // stage h[4x300] from coherence point into LDS (8B relaxed atomic loads)
      const unsigned long long* src = (const unsigned long long*)
          (h_buf + (size_t)(s & 1) * B_ * H_ + (size_t)brbase * H_);
      for (int i = tid; i < 600; i += 512) {
        unsigned long long v = __hip_atomic_load(&src[i], __ATOMIC_RELAXED, __HIP_MEMORY_SCOPE_AGENT);
        union { unsigned long long u; float f[2]; } cv; cv.u = v;
        int e = i * 2;
        int r = e / 300, k = e - r * 300;
        lds_h[r * 308 + (k / 75) * 76 + (k % 75)] = cv.f[0];
        e++;
        r = e / 300; k = e - r * 300;
        lds_h[r * 308 + (k / 75) * 76 + (k % 75)] = cv.f[1];
      }
    }
    __syncthreads();

    float a0 = 0.f, a1 = 0.f, a2 = 0.f, a3 = 0.f;
    if (ccv && s > 0) {
      const int kb = ks * 76;
      #pragma unroll
      for (int kk = 0; kk < 72; kk += 4) {
        float4 h0 = *(const float4*)&lds_h[0 * 308 + kb + kk];
        float4 h1 = *(const float4*)&lds_h[1 * 308 + kb + kk];
        float4 h2 = *(const float4*)&lds_h[2 * 308 + kb + kk];
        float4 h3 = *(const float4*)&lds_h[3 * 308 + kb + kk];
        float w0 = w[kk], w1 = w[kk + 1], w2 = w[kk + 2], w3 = w[kk + 3];
        a0 += h0.x * w0 + h0.y * w1 + h0.z * w2 + h0.w * w3;
        a1 += h1.x * w0 + h1.y * w1 + h1.z * w2 + h1.w * w3;
        a2 += h2.x * w0 + h2.y * w1 + h2.z * w2 + h2.w * w3;
        a3 += h3.x * w0 + h3.y * w1 + h3.z * w2 + h3.w * w3;
      }
      #pragma unroll
      for (int kk = 72; kk < 75; kk++) {
        float wv = w[kk];
        a0 += lds_h[0 * 308 + kb + kk] * wv;
        a1 += lds_h[1 * 308 + kb + kk] * wv;
        a2 += lds_h[2 * 308 + kb + kk] * wv;
        a3 += lds_h[3 * 308 + kb + kk] * wv;
      }
    }
    if (ccv) {
      zpart[(ks * 4 + 0) * 128 + cc] = a0;
      zpart[(ks * 4 + 1) * 128 + cc] = a1;
      zpart[(ks * 4 + 2) * 128 + cc] = a2;
      zpart[(ks * 4 + 3) * 128 + cc] = a3;
    }
    __syncthreads();
    if (tid < 500) {
      float z = zpart[(0 * 4 + r2) * 128 + cc2] + zpart[(1 * 4 + r2) * 128 + cc2]
              + zpart[(2 * 4 + r2) * 128 + cc2] + zpart[(3 * 4 + r2) * 128 + cc2]
              + pi_pre + bias_s[cc2];
      zfull[r2 * 128 + cc2] = z;
    }
    __syncthreads();
    if (tid < 100) {
      int lr = len_s[gr];
      if (s < lr) {
        float zi = zfull[gr * 128 + gj];
        float zf = zfull[gr * 128 + 25 + gj];
        float zg = zfull[gr * 128 + 50 + gj];
        float zo = zfull[gr * 128 + 75 + gj];
        float zr = zfull[gr * 128 + 100 + gj];
        float ii = sigf(zi), ff = sigf(zf), gg = tanhf_(zg);
        float oo = sigf(zo), rr = sigf(zr);
        float cn = ii * gg + ff * c_lds[tid];
        c_lds[tid] = cn;
        float hn = rr * (oo * tanhf_(cn)) + (1.f - rr) * pi6_pre;
        int t = rev ? (lr - 1 - s) : s;
        int br = brbase + gr;
        // coherent (relaxed agent) store of h for cross-block consumers
        __hip_atomic_store(&h_buf[(size_t)((s + 1) & 1) * B_ * H_ + (size_t)br * H_ + j2],
                           hn, __ATOMIC_RELAXED, __HIP_MEMORY_SCOPE_AGENT);
        hid[((size_t)t * B_ + br) * H_ + j2] = hn;                 // plain: next-kernel read
        xb[((size_t)t * B_ + br) * H_ + j2] = f2bf(hn);            // next layer's GEMM input
      }
    }
    // drain stores (h_buf acks at coherence point) before publishing the flag
    asm volatile("s_waitcnt vmcnt(0) lgkmcnt(0)" ::: "memory");
    __syncthreads();
    if (tid == 0)
      __hip_atomic_store(arr_g + cb, (unsigned)(s + 1),
                         __ATOMIC_RELAXED, __HIP_MEMORY_SCOPE_AGENT);
  }
}

extern "C" void kernel_launch(void* const* d_in, const int* in_sizes, int n_in,
                              void* d_out, int out_size, void* d_ws, size_t ws_size,
                              hipStream_t stream) {
  const float* inputs = (const float*)d_in[0];
  const int* lengths = (const int*)d_in[1];
  const float* W_ih0 = (const float*)d_in[2];
  const float* W_ih_rest = (const float*)d_in[3];
  const float* W_hh = (const float*)d_in[4];
  const float* b_hh = (const float*)d_in[5];
  float* outp = (float*)d_out;
  float* hidden = outp + (size_t)B_ * T_ * H_;   // [L][T,B,H]

  char* ws = (char*)d_ws;
  float* pi = (float*)ws;                                         // M_*NG fp32 (118MB)
  size_t off = (size_t)M_ * NG * 4;
  unsigned short* xb = (unsigned short*)(ws + off);               // M_*H_ bf16
  off += (size_t)M_ * H_ * 2;
  unsigned short* Wb = (unsigned short*)(ws + off);               // 4,140,000 bf16
  off += 4140000ull * 2;
  float* h_buf = (float*)(ws + off);                              // 2*64*300 fp32 (8B aligned)
  off += 2ull * B_ * H_ * 4;
  unsigned* arrive = (unsigned*)(ws + off);                       // L_*16*12 flags

  hipMemsetAsync(d_out, 0, (size_t)out_size * 4, stream);         // zero padding regions
  hipMemsetAsync(arrive, 0, L_ * 16 * 12 * 4, stream);

  {
    int n = D_ * NG + (L_ - 1) * H_ * NG;
    k_convert_w<<<(n + 255) / 256, 256, 0, stream>>>(W_ih0, W_ih_rest, Wb);
  }
  {
    int n = T_ * B_ * D_;
    k_transpose_in<<<(n + 255) / 256, 256, 0, stream>>>(inputs, xb);
  }
  for (int l = 0; l < L_; l++) {
    const unsigned short* Wihb = (l == 0) ? Wb : (Wb + 360000 + (size_t)(l - 1) * 540000);
    int K = (l == 0) ? D_ : H_;
    k_gemm<<<dim3(M_ / 64, (NG + 63) / 64), 256, 0, stream>>>(xb, Wihb, pi, K);
    float* hid_l = hidden + (size_t)l * T_ * B_ * H_;
    k_recur<<<192, 512, 0, stream>>>(pi, W_hh + (size_t)l * H_ * NZ, b_hh + (size_t)l * NZ,
                                     lengths, hid_l, xb, h_buf, arrive + l * 192, l & 1);
  }
  k_out<<<((B_ * T_ * H_) + 255) / 256, 256, 0, stream>>>(
      hidden + (size_t)(L_ - 1) * T_ * B_ * H_, outp);
}

// Round 3
// 8958.620 us; speedup vs baseline: 3.5951x; 1.0032x over previous
//
#include <hip/hip_runtime.h>
#include <hip/hip_bf16.h>

#define B_ 64
#define T_ 256
#define D_ 200
#define H_ 300
#define L_ 8
#define M_ 16384      // T_*B_
#define NG 1800       // 6H
#define NZ 1500       // 5H

typedef __attribute__((ext_vector_type(8))) short bf16x8;
typedef __attribute__((ext_vector_type(4))) float f32x4;

__device__ __forceinline__ unsigned short f2bf(float f) {
  union { float f; unsigned u; } v; v.f = f;
  unsigned r = v.u + 0x7fffu + ((v.u >> 16) & 1u);   // RNE
  return (unsigned short)(r >> 16);
}

__device__ __forceinline__ float sigf(float x) { return 1.f / (1.f + __expf(-x)); }
__device__ __forceinline__ float tanhf_(float x) {
  x = fminf(15.f, fmaxf(-15.f, x));
  float e = __expf(2.f * x);
  return (e - 1.f) / (e + 1.f);
}

// ---- weight conversion: W_ih0 (200x1800) then W_ih_rest (7x300x1800) -> bf16 ----
__global__ void k_convert_w(const float* __restrict__ W0, const float* __restrict__ Wr,
                            unsigned short* __restrict__ Wb) {
  int i = blockIdx.x * blockDim.x + threadIdx.x;
  const int n0 = D_ * NG;            // 360000
  const int n1 = (L_ - 1) * H_ * NG; // 3780000
  if (i < n0) Wb[i] = f2bf(W0[i]);
  else if (i < n0 + n1) Wb[i] = f2bf(Wr[i - n0]);
}

// ---- inputs [B,T,D] fp32 -> time-major xb [T,B,D] bf16 ----
__global__ void k_transpose_in(const float* __restrict__ inp, unsigned short* __restrict__ xb) {
  int i = blockIdx.x * blockDim.x + threadIdx.x;     // over T_*B_*D_
  if (i >= T_ * B_ * D_) return;
  int d = i % D_;
  int r = i / D_;       // t*B_+b
  int b = r % B_;
  int t = r / B_;
  xb[i] = f2bf(inp[((size_t)b * T_ + t) * D_ + d]);
}

// ---- hidden[7] [T,B,H] -> output [B,T,H] ----
__global__ void k_out(const float* __restrict__ hid7, float* __restrict__ outp) {
  int i = blockIdx.x * blockDim.x + threadIdx.x;     // over B_*T_*H_
  if (i >= B_ * T_ * H_) return;
  int j = i % H_;
  int r = i / H_;
  int t = r % T_;
  int b = r / T_;
  outp[i] = hid7[((size_t)t * B_ + b) * H_ + j];
}

// ---- pi GEMM: C[M,1800] fp32 = A[M,K] bf16 * B[K,1800] bf16 ----
__global__ __launch_bounds__(256) void k_gemm(const unsigned short* __restrict__ A,
                                              const unsigned short* __restrict__ Bw,
                                              float* __restrict__ C, int K) {
  __shared__ unsigned short As[64 * 40];
  __shared__ unsigned short Bs[64 * 40];
  int bm = blockIdx.x, bn = blockIdx.y;
  int tid = threadIdx.x;
  int lane = tid & 63, wid = tid >> 6;
  int wm = wid & 1, wn = wid >> 1;
  int l16 = lane & 15, quad = lane >> 4;
  f32x4 acc00 = {0,0,0,0}, acc01 = {0,0,0,0}, acc10 = {0,0,0,0}, acc11 = {0,0,0,0};
  int nk = (K + 31) >> 5;
  for (int kc = 0; kc < nk; kc++) {
    int k0 = kc << 5;
    #pragma unroll
    for (int c0 = 0; c0 < 2; c0++) {
      int c = tid + c0 * 256;
      int m = c >> 3, kq = (c & 7) << 2;
      int kk = k0 + kq;
      uint2 val = make_uint2(0u, 0u);
      if (kk < K) val = *(const uint2*)(A + (size_t)(bm * 64 + m) * K + kk);
      *(uint2*)(&As[m * 40 + kq]) = val;
    }
    #pragma unroll
    for (int c0 = 0; c0 < 2; c0++) {
      int c = tid + c0 * 256;
      int krow = c >> 4, nq = (c & 15) << 2;
      int col = bn * 64 + nq;
      uint2 val = make_uint2(0u, 0u);
      if ((k0 + krow) < K && col < NG)
        val = *(const uint2*)(Bw + (size_t)(k0 + krow) * NG + col);
      const unsigned short* pv = (const unsigned short*)&val;
      Bs[(nq + 0) * 40 + krow] = pv[0];
      Bs[(nq + 1) * 40 + krow] = pv[1];
      Bs[(nq + 2) * 40 + krow] = pv[2];
      Bs[(nq + 3) * 40 + krow] = pv[3];
    }
    __syncthreads();
    bf16x8 a0 = *(const bf16x8*)&As[(wm * 32 + l16) * 40 + quad * 8];
    bf16x8 a1 = *(const bf16x8*)&As[(wm * 32 + 16 + l16) * 40 + quad * 8];
    bf16x8 b0 = *(const bf16x8*)&Bs[(wn * 32 + l16) * 40 + quad * 8];
    bf16x8 b1 = *(const bf16x8*)&Bs[(wn * 32 + 16 + l16) * 40 + quad * 8];
    acc00 = __builtin_amdgcn_mfma_f32_16x16x32_bf16(a0, b0, acc00, 0, 0, 0);
    acc01 = __builtin_amdgcn_mfma_f32_16x16x32_bf16(a0, b1, acc01, 0, 0, 0);
    acc10 = __builtin_amdgcn_mfma_f32_16x16x32_bf16(a1, b0, acc10, 0, 0, 0);
    acc11 = __builtin_amdgcn_mfma_f32_16x16x32_bf16(a1, b1, acc11, 0, 0, 0);
    __syncthreads();
  }
  int rowb = bm * 64 + wm * 32 + quad * 4;
  int colb = bn * 64 + wn * 32 + l16;
  #pragma unroll
  for (int i = 0; i < 4; i++) {
    if (colb < NG) {
      C[(size_t)(rowb + i) * NG + colb] = acc00[i];
      C[(size_t)(rowb + 16 + i) * NG + colb] = acc10[i];
    }
    if (colb + 16 < NG) {
      C[(size_t)(rowb + i) * NG + colb + 16] = acc01[i];
      C[(size_t)(rowb + 16 + i) * NG + colb + 16] = acc11[i];
    }
  }
}

// ---- persistent recurrence: 192 blocks = 16 batch-groups (4 rows) x 12 column-blocks ----
// h exchange via SELF-VALIDATING packed words: (tag:u32 | h:f32bits) in one 8B relaxed
// agent atomic. No flags, no producer-side drain, no post-detect load: each thread polls
// its own 2-3 words and stashes payloads straight to LDS. Tags monotonic across layers
// (l*300+s+1), double-buffered by step parity. Frozen rows always publish (tagged,
// bounded garbage) so pollers never hang; hid/xb stores stay length-guarded.
__global__ __launch_bounds__(512, 2) void k_recur(
    const float* __restrict__ pi, const float* __restrict__ Whh,
    const float* __restrict__ bias, const int* __restrict__ lens,
    float* __restrict__ hid, unsigned short* __restrict__ xb,
    unsigned long long* __restrict__ h_words, int rev, int tagbase)
{
  __shared__ float lds_h[4 * 308];   // [r][ks*76+kk]
  __shared__ float zpart[16 * 128];  // [ks*4+r][cc]
  __shared__ float c_lds[100];
  __shared__ float bias_s[128];
  __shared__ int len_s[4];

  const int tid = threadIdx.x;
  const int bid = blockIdx.x;
  const int g = bid & 15;    // batch group
  const int cb = bid >> 4;   // column block 0..11

  const int cc = tid & 127;
  const int ks = tid >> 7;
  const bool ccv = cc < 125;
  const int gate0 = cc / 25;
  const int jj = cc % 25;
  const int colg = gate0 * 300 + cb * 25 + jj;  // z column [0,1500)

  const int gr = tid / 25;                      // gate mapping (tid<100)
  const int gj = tid - gr * 25;
  const int j2 = cb * 25 + gj;

  float w[75];
  if (ccv) {
    #pragma unroll
    for (int kk = 0; kk < 75; kk++)
      w[kk] = Whh[(size_t)(ks * 75 + kk) * NZ + colg];
  }
  if (tid < 4) len_s[tid] = lens[g * 4 + tid];
  if (tid < 125) bias_s[tid] = bias[colg];
  if (tid < 100) c_lds[tid] = 0.f;
  __syncthreads();

  int S = len_s[0];
  S = len_s[1] > S ? len_s[1] : S;
  S = len_s[2] > S ? len_s[2] : S;
  S = len_s[3] > S ? len_s[3] : S;

  unsigned long long* hw = h_words + (size_t)g * 2400;   // [parity][1200]
  const int brbase = g * 4;
  const int n2ok = (tid + 1024) < 1200;

  for (int s = 0; s < S; s++) {
    // gate threads prefetch their 6 pi values (in flight across the poll)
    float piv0 = 0.f, piv1 = 0.f, piv2 = 0.f, piv3 = 0.f, piv4 = 0.f, pi6 = 0.f;
    if (tid < 100) {
      int lr = len_s[gr];
      if (s < lr) {
        int t = rev ? (lr - 1 - s) : s;
        const float* prow = pi + ((size_t)t * B_ + (brbase + gr)) * NG;
        piv0 = prow[0 * 300 + j2];
        piv1 = prow[1 * 300 + j2];
        piv2 = prow[2 * 300 + j2];
        piv3 = prow[3 * 300 + j2];
        piv4 = prow[4 * 300 + j2];
        pi6  = prow[NZ + j2];
      }
    }

    if (s > 0) {
      const unsigned tg = (unsigned)(tagbase + s);          // tag of h_s
      const unsigned long long* buf = hw + (size_t)(s & 1) * 1200;
      unsigned long long v0, v1, v2 = 0ull;
      for (;;) {
        v0 = __hip_atomic_load(buf + tid,       __ATOMIC_RELAXED, __HIP_MEMORY_SCOPE_AGENT);
        v1 = __hip_atomic_load(buf + tid + 512, __ATOMIC_RELAXED, __HIP_MEMORY_SCOPE_AGENT);
        if (n2ok)
          v2 = __hip_atomic_load(buf + tid + 1024, __ATOMIC_RELAXED, __HIP_MEMORY_SCOPE_AGENT);
        bool ok = ((unsigned)(v0 >> 32) == tg) && ((unsigned)(v1 >> 32) == tg);
        if (n2ok) ok = ok && ((unsigned)(v2 >> 32) == tg);
        if (ok) break;
      }
      // stash payloads to LDS
      {
        int wd = tid;
        int r = wd / 300, k = wd - r * 300;
        union { unsigned u; float f; } cv; cv.u = (unsigned)v0;
        lds_h[r * 308 + (k / 75) * 76 + (k % 75)] = cv.f;
        wd = tid + 512; r = wd / 300; k = wd - r * 300;
        cv.u = (unsigned)v1;
        lds_h[r * 308 + (k / 75) * 76 + (k % 75)] = cv.f;
        if (n2ok) {
          wd = tid + 1024; r = wd / 300; k = wd - r * 300;
          cv.u = (unsigned)v2;
          lds_h[r * 308 + (k / 75) * 76 + (k % 75)] = cv.f;
        }
      }
    }
    __syncthreads();

    float a0 = 0.f, a1 = 0.f, a2 = 0.f, a3 = 0.f;
    if (ccv && s > 0) {
      const int kb = ks * 76;
      #pragma unroll
      for (int kk = 0; kk < 72; kk += 4) {
        float4 h0 = *(const float4*)&lds_h[0 * 308 + kb + kk];
        float4 h1 = *(const float4*)&lds_h[1 * 308 + kb + kk];
        float4 h2 = *(const float4*)&lds_h[2 * 308 + kb + kk];
        float4 h3 = *(const float4*)&lds_h[3 * 308 + kb + kk];
        float w0 = w[kk], w1 = w[kk + 1], w2 = w[kk + 2], w3 = w[kk + 3];
        a0 += h0.x * w0 + h0.y * w1 + h0.z * w2 + h0.w * w3;
        a1 += h1.x * w0 + h1.y * w1 + h1.z * w2 + h1.w * w3;
        a2 += h2.x * w0 + h2.y * w1 + h2.z * w2 + h2.w * w3;
        a3 += h3.x * w0 + h3.y * w1 + h3.z * w2 + h3.w * w3;
      }
      #pragma unroll
      for (int kk = 72; kk < 75; kk++) {
        float wv = w[kk];
        a0 += lds_h[0 * 308 + kb + kk] * wv;
        a1 += lds_h[1 * 308 + kb + kk] * wv;
        a2 += lds_h[2 * 308 + kb + kk] * wv;
        a3 += lds_h[3 * 308 + kb + kk] * wv;
      }
    }
    if (ccv) {
      zpart[(ks * 4 + 0) * 128 + cc] = a0;
      zpart[(ks * 4 + 1) * 128 + cc] = a1;
      zpart[(ks * 4 + 2) * 128 + cc] = a2;
      zpart[(ks * 4 + 3) * 128 + cc] = a3;
    }
    __syncthreads();

    if (tid < 100) {
      // fused z-sum + gates
      float z0, z1, z2, z3, z4;
      {
        int c = 0 * 25 + gj;
        z0 = zpart[(0 * 4 + gr) * 128 + c] + zpart[(1 * 4 + gr) * 128 + c]
           + zpart[(2 * 4 + gr) * 128 + c] + zpart[(3 * 4 + gr) * 128 + c]
           + piv0 + bias_s[c];
        c = 1 * 25 + gj;
        z1 = zpart[(0 * 4 + gr) * 128 + c] + zpart[(1 * 4 + gr) * 128 + c]
           + zpart[(2 * 4 + gr) * 128 + c] + zpart[(3 * 4 + gr) * 128 + c]
           + piv1 + bias_s[c];
        c = 2 * 25 + gj;
        z2 = zpart[(0 * 4 + gr) * 128 + c] + zpart[(1 * 4 + gr) * 128 + c]
           + zpart[(2 * 4 + gr) * 128 + c] + zpart[(3 * 4 + gr) * 128 + c]
           + piv2 + bias_s[c];
        c = 3 * 25 + gj;
        z3 = zpart[(0 * 4 + gr) * 128 + c] + zpart[(1 * 4 + gr) * 128 + c]
           + zpart[(2 * 4 + gr) * 128 + c] + zpart[(3 * 4 + gr) * 128 + c]
           + piv3 + bias_s[c];
        c = 4 * 25 + gj;
        z4 = zpart[(0 * 4 + gr) * 128 + c] + zpart[(1 * 4 + gr) * 128 + c]
           + zpart[(2 * 4 + gr) * 128 + c] + zpart[(3 * 4 + gr) * 128 + c]
           + piv4 + bias_s[c];
      }
      float ii = sigf(z0), ff = sigf(z1), gg = tanhf_(z2);
      float oo = sigf(z3), rr = sigf(z4);
      float cn = ii * gg + ff * c_lds[tid];
      c_lds[tid] = cn;
      float hn = rr * (oo * tanhf_(cn)) + (1.f - rr) * pi6;
      // always publish (self-validating word); frozen rows carry bounded garbage
      union { float f; unsigned u; } hb; hb.f = hn;
      unsigned long long word = (((unsigned long long)(unsigned)(tagbase + s + 1)) << 32) | hb.u;
      __hip_atomic_store(&hw[(size_t)((s + 1) & 1) * 1200 + gr * 300 + j2], word,
                         __ATOMIC_RELAXED, __HIP_MEMORY_SCOPE_AGENT);
      int lr = len_s[gr];
      if (s < lr) {
        int t = rev ? (lr - 1 - s) : s;
        int br = brbase + gr;
        hid[((size_t)t * B_ + br) * H_ + j2] = hn;
        xb[((size_t)t * B_ + br) * H_ + j2] = f2bf(hn);
      }
    }
  }
}

extern "C" void kernel_launch(void* const* d_in, const int* in_sizes, int n_in,
                              void* d_out, int out_size, void* d_ws, size_t ws_size,
                              hipStream_t stream) {
  const float* inputs = (const float*)d_in[0];
  const int* lengths = (const int*)d_in[1];
  const float* W_ih0 = (const float*)d_in[2];
  const float* W_ih_rest = (const float*)d_in[3];
  const float* W_hh = (const float*)d_in[4];
  const float* b_hh = (const float*)d_in[5];
  float* outp = (float*)d_out;
  float* hidden = outp + (size_t)B_ * T_ * H_;   // [L][T,B,H]

  char* ws = (char*)d_ws;
  float* pi = (float*)ws;                                         // M_*NG fp32 (118MB)
  size_t off = (size_t)M_ * NG * 4;
  unsigned short* xb = (unsigned short*)(ws + off);               // M_*H_ bf16
  off += (size_t)M_ * H_ * 2;
  unsigned short* Wb = (unsigned short*)(ws + off);               // 4,140,000 bf16
  off += 4140000ull * 2;
  unsigned long long* h_words = (unsigned long long*)(ws + off);  // 16 groups * 2 * 1200 words
  off += 16ull * 2400 * 8;

  hipMemsetAsync(d_out, 0, (size_t)out_size * 4, stream);         // zero padding regions
  hipMemsetAsync(h_words, 0, 16ull * 2400 * 8, stream);           // clear tags (re-poisoned ws)

  {
    int n = D_ * NG + (L_ - 1) * H_ * NG;
    k_convert_w<<<(n + 255) / 256, 256, 0, stream>>>(W_ih0, W_ih_rest, Wb);
  }
  {
    int n = T_ * B_ * D_;
    k_transpose_in<<<(n + 255) / 256, 256, 0, stream>>>(inputs, xb);
  }
  for (int l = 0; l < L_; l++) {
    const unsigned short* Wihb = (l == 0) ? Wb : (Wb + 360000 + (size_t)(l - 1) * 540000);
    int K = (l == 0) ? D_ : H_;
    k_gemm<<<dim3(M_ / 64, (NG + 63) / 64), 256, 0, stream>>>(xb, Wihb, pi, K);
    float* hid_l = hidden + (size_t)l * T_ * B_ * H_;
    k_recur<<<192, 512, 0, stream>>>(pi, W_hh + (size_t)l * H_ * NZ, b_hh + (size_t)l * NZ,
                                     lengths, hid_l, xb, h_words, l & 1, l * 300);
  }
  k_out<<<((B_ * T_ * H_) + 255) / 256, 256, 0, stream>>>(
      hidden + (size_t)(L_ - 1) * T_ * B_ * H_, outp);
}

// Round 4
// 5356.885 us; speedup vs baseline: 6.0123x; 1.6724x over previous
//
#include <hip/hip_runtime.h>
#include <hip/hip_bf16.h>

#define B_ 64
#define T_ 256
#define D_ 200
#define H_ 300
#define L_ 8
#define M_ 16384      // T_*B_
#define NG 1800       // 6H
#define NZ 1500       // 5H

typedef __attribute__((ext_vector_type(8))) short bf16x8;
typedef __attribute__((ext_vector_type(4))) float f32x4;

__device__ __forceinline__ unsigned short f2bf(float f) {
  union { float f; unsigned u; } v; v.f = f;
  unsigned r = v.u + 0x7fffu + ((v.u >> 16) & 1u);   // RNE
  return (unsigned short)(r >> 16);
}

__device__ __forceinline__ float sigf(float x) { return 1.f / (1.f + __expf(-x)); }
__device__ __forceinline__ float tanhf_(float x) {
  x = fminf(15.f, fmaxf(-15.f, x));
  float e = __expf(2.f * x);
  return (e - 1.f) / (e + 1.f);
}

// ---- weight conversion: W_ih0 (200x1800) then W_ih_rest (7x300x1800) -> bf16 ----
__global__ void k_convert_w(const float* __restrict__ W0, const float* __restrict__ Wr,
                            unsigned short* __restrict__ Wb) {
  int i = blockIdx.x * blockDim.x + threadIdx.x;
  const int n0 = D_ * NG;            // 360000
  const int n1 = (L_ - 1) * H_ * NG; // 3780000
  if (i < n0) Wb[i] = f2bf(W0[i]);
  else if (i < n0 + n1) Wb[i] = f2bf(Wr[i - n0]);
}

// ---- inputs [B,T,D] fp32 -> time-major xb [T,B,D] bf16 ----
__global__ void k_transpose_in(const float* __restrict__ inp, unsigned short* __restrict__ xb) {
  int i = blockIdx.x * blockDim.x + threadIdx.x;     // over T_*B_*D_
  if (i >= T_ * B_ * D_) return;
  int d = i % D_;
  int r = i / D_;       // t*B_+b
  int b = r % B_;
  int t = r / B_;
  xb[i] = f2bf(inp[((size_t)b * T_ + t) * D_ + d]);
}

// ---- hidden[7] [T,B,H] -> output [B,T,H] ----
__global__ void k_out(const float* __restrict__ hid7, float* __restrict__ outp) {
  int i = blockIdx.x * blockDim.x + threadIdx.x;     // over B_*T_*H_
  if (i >= B_ * T_ * H_) return;
  int j = i % H_;
  int r = i / H_;
  int t = r % T_;
  int b = r / T_;
  outp[i] = hid7[((size_t)t * B_ + b) * H_ + j];
}

// ---- pi GEMM: C[M,1800] fp32 = A[M,K] bf16 * B[K,1800] bf16 ----
__global__ __launch_bounds__(256) void k_gemm(const unsigned short* __restrict__ A,
                                              const unsigned short* __restrict__ Bw,
                                              float* __restrict__ C, int K) {
  __shared__ unsigned short As[64 * 40];
  __shared__ unsigned short Bs[64 * 40];
  int bm = blockIdx.x, bn = blockIdx.y;
  int tid = threadIdx.x;
  int lane = tid & 63, wid = tid >> 6;
  int wm = wid & 1, wn = wid >> 1;
  int l16 = lane & 15, quad = lane >> 4;
  f32x4 acc00 = {0,0,0,0}, acc01 = {0,0,0,0}, acc10 = {0,0,0,0}, acc11 = {0,0,0,0};
  int nk = (K + 31) >> 5;
  for (int kc = 0; kc < nk; kc++) {
    int k0 = kc << 5;
    #pragma unroll
    for (int c0 = 0; c0 < 2; c0++) {
      int c = tid + c0 * 256;
      int m = c >> 3, kq = (c & 7) << 2;
      int kk = k0 + kq;
      uint2 val = make_uint2(0u, 0u);
      if (kk < K) val = *(const uint2*)(A + (size_t)(bm * 64 + m) * K + kk);
      *(uint2*)(&As[m * 40 + kq]) = val;
    }
    #pragma unroll
    for (int c0 = 0; c0 < 2; c0++) {
      int c = tid + c0 * 256;
      int krow = c >> 4, nq = (c & 15) << 2;
      int col = bn * 64 + nq;
      uint2 val = make_uint2(0u, 0u);
      if ((k0 + krow) < K && col < NG)
        val = *(const uint2*)(Bw + (size_t)(k0 + krow) * NG + col);
      const unsigned short* pv = (const unsigned short*)&val;
      Bs[(nq + 0) * 40 + krow] = pv[0];
      Bs[(nq + 1) * 40 + krow] = pv[1];
      Bs[(nq + 2) * 40 + krow] = pv[2];
      Bs[(nq + 3) * 40 + krow] = pv[3];
    }
    __syncthreads();
    bf16x8 a0 = *(const bf16x8*)&As[(wm * 32 + l16) * 40 + quad * 8];
    bf16x8 a1 = *(const bf16x8*)&As[(wm * 32 + 16 + l16) * 40 + quad * 8];
    bf16x8 b0 = *(const bf16x8*)&Bs[(wn * 32 + l16) * 40 + quad * 8];
    bf16x8 b1 = *(const bf16x8*)&Bs[(wn * 32 + 16 + l16) * 40 + quad * 8];
    acc00 = __builtin_amdgcn_mfma_f32_16x16x32_bf16(a0, b0, acc00, 0, 0, 0);
    acc01 = __builtin_amdgcn_mfma_f32_16x16x32_bf16(a0, b1, acc01, 0, 0, 0);
    acc10 = __builtin_amdgcn_mfma_f32_16x16x32_bf16(a1, b0, acc10, 0, 0, 0);
    acc11 = __builtin_amdgcn_mfma_f32_16x16x32_bf16(a1, b1, acc11, 0, 0, 0);
    __syncthreads();
  }
  int rowb = bm * 64 + wm * 32 + quad * 4;
  int colb = bn * 64 + wn * 32 + l16;
  #pragma unroll
  for (int i = 0; i < 4; i++) {
    if (colb < NG) {
      C[(size_t)(rowb + i) * NG + colb] = acc00[i];
      C[(size_t)(rowb + 16 + i) * NG + colb] = acc10[i];
    }
    if (colb + 16 < NG) {
      C[(size_t)(rowb + i) * NG + colb + 16] = acc01[i];
      C[(size_t)(rowb + 16 + i) * NG + colb + 16] = acc11[i];
    }
  }
}

// ---- persistent recurrence: 192 blocks = 16 batch-groups (4 rows) x 12 column-blocks ----
// Dot z[4x125] = h[4x300] @ Whh[300x125] done by MFMA (M padded to 16, K to 320,
// N=128 = 8 tiles, one per wave). Whh B-frags preloaded in VGPRs (40/thread).
// h exchange: u32 (tag16<<16 | bf16) self-validating words, relaxed agent atomics,
// parity double-buffered; tags monotonic across layers. R3's 608 broadcast
// ds_read_b128/step collapse to ~90 LDS instrs + 10 MFMA per wave.
__global__ __launch_bounds__(512, 2) void k_recur(
    const float* __restrict__ pi, const float* __restrict__ Whh,
    const float* __restrict__ bias, const int* __restrict__ lens,
    float* __restrict__ hid, unsigned short* __restrict__ xb,
    unsigned* __restrict__ h_words, int rev, int tagbase)
{
  __shared__ __align__(16) unsigned short h_lds[16 * 328]; // bf16 [row][k], rows 4-15 & k>=300 zero
  __shared__ __align__(16) float z_lds[128 * 4];           // [n][r]
  __shared__ float c_lds[100];
  __shared__ float bias_s[128];
  __shared__ int len_s[4];

  const int tid = threadIdx.x;
  const int bid = blockIdx.x;
  const int g = bid & 15;    // batch group
  const int cb = bid >> 4;   // column block 0..11

  const int lane = tid & 63;
  const int wid = tid >> 6;          // 0..7 = N-tile index
  const int l16 = lane & 15;
  const int quad = lane >> 4;

  const int gr = tid / 25;           // gate mapping (tid<100): row
  const int gj = tid - gr * 25;      // j within 25
  const int j2 = cb * 25 + gj;

  // ---- preload Whh B-fragments: wfrag[c], n = wid*16+l16, k = c*32+quad*8+j ----
  bf16x8 wfrag[10];
  {
    int n = wid * 16 + l16;
    bool vn = n < 125;
    int colw = vn ? ((n / 25) * 300 + cb * 25 + (n % 25)) : 0;
    #pragma unroll
    for (int c = 0; c < 10; c++) {
      bf16x8 f;
      #pragma unroll
      for (int j = 0; j < 8; j++) {
        int k = c * 32 + quad * 8 + j;
        float v = (vn && k < 300) ? Whh[(size_t)k * NZ + colw] : 0.f;
        f[j] = (short)f2bf(v);
      }
      wfrag[c] = f;
    }
  }
  if (tid < 4) len_s[tid] = lens[g * 4 + tid];
  if (tid < 125) bias_s[tid] = bias[(tid / 25) * 300 + cb * 25 + (tid % 25)];
  if (tid < 100) c_lds[tid] = 0.f;
  for (int i = tid; i < 16 * 328; i += 512) h_lds[i] = 0;  // zero pad rows/cols
  __syncthreads();

  int S = len_s[0];
  S = len_s[1] > S ? len_s[1] : S;
  S = len_s[2] > S ? len_s[2] : S;
  S = len_s[3] > S ? len_s[3] : S;

  unsigned* hw = h_words + (size_t)g * 2400;   // [parity][1200] u32
  const int brbase = g * 4;
  const bool p2 = (tid + 1024) < 1200;

  for (int s = 0; s < S; s++) {
    // gate threads prefetch their 6 pi values (in flight across the poll)
    float piv0 = 0.f, piv1 = 0.f, piv2 = 0.f, piv3 = 0.f, piv4 = 0.f, pi6 = 0.f;
    if (tid < 100) {
      int lr = len_s[gr];
      if (s < lr) {
        int t = rev ? (lr - 1 - s) : s;
        const float* prow = pi + ((size_t)t * B_ + (brbase + gr)) * NG;
        piv0 = prow[0 * 300 + j2];
        piv1 = prow[1 * 300 + j2];
        piv2 = prow[2 * 300 + j2];
        piv3 = prow[3 * 300 + j2];
        piv4 = prow[4 * 300 + j2];
        pi6  = prow[NZ + j2];
      }
    }

    if (s > 0) {
      const unsigned tg = (unsigned)(tagbase + s);          // tag of h_s
      const unsigned* buf = hw + (size_t)(s & 1) * 1200;
      unsigned v0, v1, v2 = 0u;
      for (;;) {
        v0 = __hip_atomic_load(buf + tid,       __ATOMIC_RELAXED, __HIP_MEMORY_SCOPE_AGENT);
        v1 = __hip_atomic_load(buf + tid + 512, __ATOMIC_RELAXED, __HIP_MEMORY_SCOPE_AGENT);
        if (p2)
          v2 = __hip_atomic_load(buf + tid + 1024, __ATOMIC_RELAXED, __HIP_MEMORY_SCOPE_AGENT);
        bool ok = ((v0 >> 16) == tg) && ((v1 >> 16) == tg);
        if (p2) ok = ok && ((v2 >> 16) == tg);
        if (ok) break;
      }
      // stash bf16 payloads into LDS A-operand layout
      int wd = tid, r = wd / 300, k = wd - r * 300;
      h_lds[r * 328 + k] = (unsigned short)v0;
      wd = tid + 512; r = wd / 300; k = wd - r * 300;
      h_lds[r * 328 + k] = (unsigned short)v1;
      if (p2) {
        wd = tid + 1024; r = wd / 300; k = wd - r * 300;
        h_lds[r * 328 + k] = (unsigned short)v2;
      }
    }
    __syncthreads();

    f32x4 acc = {0, 0, 0, 0};
    if (s > 0) {
      f32x4 acc2 = {0, 0, 0, 0};
      const unsigned short* abase = &h_lds[l16 * 328 + quad * 8];
      #pragma unroll
      for (int c = 0; c < 10; c += 2) {
        bf16x8 a0 = *(const bf16x8*)(abase + c * 32);
        bf16x8 a1 = *(const bf16x8*)(abase + c * 32 + 32);
        acc  = __builtin_amdgcn_mfma_f32_16x16x32_bf16(a0, wfrag[c],     acc,  0, 0, 0);
        acc2 = __builtin_amdgcn_mfma_f32_16x16x32_bf16(a1, wfrag[c + 1], acc2, 0, 0, 0);
      }
      acc += acc2;
    }
    // C layout: col=lane&15, row=quad*4+reg -> lanes 0-15 hold rows 0-3 in regs 0-3
    if (quad == 0) {
      int n = wid * 16 + l16;
      *(f32x4*)&z_lds[n * 4] = acc;
    }
    __syncthreads();

    if (tid < 100) {
      float z0 = z_lds[(gj       ) * 4 + gr] + piv0 + bias_s[gj];
      float z1 = z_lds[( 25 + gj ) * 4 + gr] + piv1 + bias_s[25 + gj];
      float z2 = z_lds[( 50 + gj ) * 4 + gr] + piv2 + bias_s[50 + gj];
      float z3 = z_lds[( 75 + gj ) * 4 + gr] + piv3 + bias_s[75 + gj];
      float z4 = z_lds[(100 + gj ) * 4 + gr] + piv4 + bias_s[100 + gj];
      float ii = sigf(z0), ff = sigf(z1), gg = tanhf_(z2);
      float oo = sigf(z3), rr = sigf(z4);
      float cn = ii * gg + ff * c_lds[tid];
      c_lds[tid] = cn;
      float hn = rr * (oo * tanhf_(cn)) + (1.f - rr) * pi6;
      unsigned short hb = f2bf(hn);
      unsigned word = ((unsigned)(tagbase + s + 1) << 16) | (unsigned)hb;
      __hip_atomic_store(&hw[(size_t)((s + 1) & 1) * 1200 + gr * 300 + j2], word,
                         __ATOMIC_RELAXED, __HIP_MEMORY_SCOPE_AGENT);
      int lr = len_s[gr];
      if (s < lr) {
        int t = rev ? (lr - 1 - s) : s;
        int br = brbase + gr;
        hid[((size_t)t * B_ + br) * H_ + j2] = hn;
        xb[((size_t)t * B_ + br) * H_ + j2] = hb;
      }
    }
    // no trailing barrier needed: next stash can only start after our own gates
    // publish (we poll our own words too); h_lds/z_lds hazards separated by the
    // two barriers above.
  }
}

extern "C" void kernel_launch(void* const* d_in, const int* in_sizes, int n_in,
                              void* d_out, int out_size, void* d_ws, size_t ws_size,
                              hipStream_t stream) {
  const float* inputs = (const float*)d_in[0];
  const int* lengths = (const int*)d_in[1];
  const float* W_ih0 = (const float*)d_in[2];
  const float* W_ih_rest = (const float*)d_in[3];
  const float* W_hh = (const float*)d_in[4];
  const float* b_hh = (const float*)d_in[5];
  float* outp = (float*)d_out;
  float* hidden = outp + (size_t)B_ * T_ * H_;   // [L][T,B,H]

  char* ws = (char*)d_ws;
  float* pi = (float*)ws;                                         // M_*NG fp32 (118MB)
  size_t off = (size_t)M_ * NG * 4;
  unsigned short* xb = (unsigned short*)(ws + off);               // M_*H_ bf16
  off += (size_t)M_ * H_ * 2;
  unsigned short* Wb = (unsigned short*)(ws + off);               // 4,140,000 bf16
  off += 4140000ull * 2;
  unsigned* h_words = (unsigned*)(ws + off);                      // 16 groups * 2 * 1200 u32
  off += 16ull * 2400 * 4;

  hipMemsetAsync(d_out, 0, (size_t)out_size * 4, stream);         // zero padding regions
  hipMemsetAsync(h_words, 0, 16ull * 2400 * 4, stream);           // clear tags

  {
    int n = D_ * NG + (L_ - 1) * H_ * NG;
    k_convert_w<<<(n + 255) / 256, 256, 0, stream>>>(W_ih0, W_ih_rest, Wb);
  }
  {
    int n = T_ * B_ * D_;
    k_transpose_in<<<(n + 255) / 256, 256, 0, stream>>>(inputs, xb);
  }
  for (int l = 0; l < L_; l++) {
    const unsigned short* Wihb = (l == 0) ? Wb : (Wb + 360000 + (size_t)(l - 1) * 540000);
    int K = (l == 0) ? D_ : H_;
    k_gemm<<<dim3(M_ / 64, (NG + 63) / 64), 256, 0, stream>>>(xb, Wihb, pi, K);
    float* hid_l = hidden + (size_t)l * T_ * B_ * H_;
    k_recur<<<192, 512, 0, stream>>>(pi, W_hh + (size_t)l * H_ * NZ, b_hh + (size_t)l * NZ,
                                     lengths, hid_l, xb, h_words, l & 1, l * 300);
  }
  k_out<<<((B_ * T_ * H_) + 255) / 256, 256, 0, stream>>>(
      hidden + (size_t)(L_ - 1) * T_ * B_ * H_, outp);
}